// Round 9
// baseline (55.375 us; speedup 1.0000x reference)
//
#include <hip/hip_runtime.h>
#include <math.h>

#define BATCH 64
#define H 512
#define W 512
#define KRAD 15
#define STRIP 32               // output rows per block
#define NSTRIP (H / STRIP)     // 16 strips per image
#define RING 40                // LDS ring slots (bf16 hsum rows); live range = 39

__device__ __forceinline__ float wave_reduce(float v) {
    #pragma unroll
    for (int off = 32; off > 0; off >>= 1) v += __shfl_xor(v, off);
    return v;
}

// f32 -> bf16 bits (round-to-nearest-even)
__device__ __forceinline__ unsigned bf16b(float f) {
    unsigned u = __float_as_uint(f);
    return (u + 0x7FFFu + ((u >> 16) & 1u)) >> 16;
}
__device__ __forceinline__ float fbf16(unsigned short s) {
    return __uint_as_float(((unsigned)s) << 16);
}

__device__ __forceinline__ void load_row(const float* __restrict__ base, int r, int lane,
                                         float4& a, float4& b) {
    if (0 <= r && r < H) {
        const float4* p4 = reinterpret_cast<const float4*>(base + (size_t)r * W + lane * 8);
        a = p4[0]; b = p4[1];
    } else {
        a = make_float4(0.f, 0.f, 0.f, 0.f);
        b = a;
    }
}

// Wave-wide horizontal 31-box-sum of one row (from registers), bf16-pack to LDS.
__device__ __forceinline__ void scan_store(float4 va, float4 vb, int lane,
                                           unsigned short* dst) {
    float v[8] = {va.x, va.y, va.z, va.w, vb.x, vb.y, vb.z, vb.w};
    float P[8];
    float run = 0.f;
    #pragma unroll
    for (int k = 0; k < 8; ++k) { run += v[k]; P[k] = run; }
    float scan = run;
    #pragma unroll
    for (int off = 1; off < 64; off <<= 1) {
        float n = __shfl_up(scan, off);
        if (lane >= off) scan += n;
    }
    const float excl = scan - run;
    #pragma unroll
    for (int k = 0; k < 8; ++k) P[k] += excl;        // inclusive prefix at x=8*lane+k
    const float total = __shfl(P[7], 63);
    // out[x] = P[min(x+15,511)] - (x>=16 ? P[x-16] : 0)
    float shA[8], shB[8];
    shA[0] = __shfl_down(P[7], 1);
    #pragma unroll
    for (int k = 1; k < 8; ++k) shA[k] = __shfl_down(P[k - 1], 2);
    #pragma unroll
    for (int k = 0; k < 8; ++k) shB[k] = __shfl_up(P[k], 2);
    const int xb = lane * 8;
    float o[8];
    #pragma unroll
    for (int k = 0; k < 8; ++k) {
        const int x = xb + k;
        const float A  = (x + KRAD <= W - 1) ? shA[k] : total;
        const float Bv = (x >= KRAD + 1) ? shB[k] : 0.f;
        o[k] = A - Bv;
    }
    uint4 wv;
    wv.x = bf16b(o[0]) | (bf16b(o[1]) << 16);
    wv.y = bf16b(o[2]) | (bf16b(o[3]) << 16);
    wv.z = bf16b(o[4]) | (bf16b(o[5]) << 16);
    wv.w = bf16b(o[6]) | (bf16b(o[7]) << 16);
    *reinterpret_cast<uint4*>(dst + xb) = wv;        // 16B, conflict-free
}

// -------- Fused: horizontal scan -> 40-slot bf16 LDS ring -> vertical window + loss.
// Geometry: LDS = 40*512*2 = 40960 B -> exactly 4 blocks/CU (160 KiB), grid 1024
// = 4 blocks/CU resident. Ring slot bases tracked incrementally:
//   sA = (8g+31) % 40  (store base / addv base), sA+k <= 46 -> one cond-sub
//   sB =  8g     % 40  (subv base), sB+i <= 31  -> no wrap
__global__ __launch_bounds__(512) void fused_kernel(const float* __restrict__ pred,
                                                    const float* __restrict__ mask,
                                                    float2* __restrict__ partials) {
    __shared__ unsigned short ring[RING][W];             // 40960 B exactly

    const int tid  = threadIdx.x;
    const int wave = tid >> 6;
    const int lane = tid & 63;
    const int img   = blockIdx.x >> 4;                   // NSTRIP = 16
    const int strip = blockIdx.x & 15;
    const int r0 = strip * STRIP;
    const int c  = tid;
    const float* mk = mask + (size_t)img * (H * W);
    const float* pr = pred + (size_t)img * (H * W);

    // Prologue: fill slots 0..30 (rows r0-16 .. r0+14)
    #pragma unroll
    for (int gp = 0; gp < 4; ++gp) {
        const int idx = gp * 8 + wave;
        if (idx < 31) {
            float4 la, lb;
            load_row(mk, r0 - 16 + idx, lane, la, lb);
            scan_store(la, lb, lane, &ring[idx][0]);
        }
    }
    __syncthreads();

    // Initial vertical sum: slots 1..30 (rows r0-15 .. r0+14)
    float vsum = 0.f;
    #pragma unroll
    for (int s = 1; s <= 30; ++s) vsum += fbf16(ring[s][c]);

    float s0 = 0.f, s1 = 0.f;
    const float inv_k2 = 1.0f / 961.0f;
    int sA = 31;   // (8g+31) % 40
    int sB = 0;    //  8g     % 40

    for (int g = 0; g < STRIP / 8; ++g) {
        const int ybase = r0 + 8 * g;

        // Issue ALL of this group's global loads up front (18 in flight),
        // then do scan arithmetic; __syncthreads' vmcnt drain completes m/p.
        float4 sa, sb;
        load_row(mk, ybase + 15 + wave, lane, sa, sb);   // scan input row
        float m[8], p[8];
        #pragma unroll
        for (int i = 0; i < 8; ++i) {
            const int y = ybase + i;
            m[i] = mk[(size_t)y * W + c];
            p[i] = pr[(size_t)y * W + c];
        }

        // Phase A: scan row ybase+15+wave into slot (sA+wave) mod 40
        {
            int slot = sA + wave;
            if (slot >= RING) slot -= RING;
            scan_store(sa, sb, lane, &ring[slot][0]);
        }
        __syncthreads();

        // Phase B: LDS window reads + register math (m/p already resident)
        float addv[8], subv[8];
        #pragma unroll
        for (int i = 0; i < 8; ++i) {
            int slotA = sA + i;
            if (slotA >= RING) slotA -= RING;
            addv[i] = fbf16(ring[slotA][c]);
            subv[i] = fbf16(ring[sB + i][c]);            // sB+i <= 31, never wraps
        }
        #pragma unroll
        for (int i = 0; i < 8; ++i) {
            vsum += addv[i] - subv[i];                   // window [y-15, y+15]
            const float avg = vsum * inv_k2;
            const float w = 1.0f + 5.0f * fabsf(avg - m[i]);
            const float e = __expf(-fabsf(p[i]));
            const float softplus = __logf(1.0f + e);     // log1p(e), e in (0,1]
            const float bce = fmaxf(p[i], 0.0f) - p[i] * m[i] + softplus;
            const float r1pe = __builtin_amdgcn_rcpf(1.0f + e);
            const float sig = (p[i] >= 0.0f) ? r1pe : e * r1pe;
            const float inter = sig * m[i];
            const float denom = sig + m[i] - inter + 1.0f;  // union - inter + 1
            const float iou = 1.0f - (inter + 1.0f) * __builtin_amdgcn_rcpf(denom);
            s0 += w;
            s1 += w * (bce + iou);
        }
        sA += 8; if (sA >= RING) sA -= RING;
        sB += 8; if (sB >= RING) sB -= RING;
        __syncthreads();   // ring slots free to overwrite next group
    }

    s0 = wave_reduce(s0);
    s1 = wave_reduce(s1);
    float2* wacc = reinterpret_cast<float2*>(&ring[0][0]);   // alias: ring dead now
    if (lane == 0) wacc[wave] = make_float2(s0, s1);
    __syncthreads();
    if (tid == 0) {
        float a0 = 0.f, a1 = 0.f;
        #pragma unroll
        for (int i = 0; i < 8; ++i) { a0 += wacc[i].x; a1 += wacc[i].y; }
        partials[blockIdx.x] = make_float2(a0, a1);
    }
}

// -------- Finalize: per-image ratio, mean over 64 images. One wave.
__global__ void finalize_kernel(const float2* __restrict__ partials,
                                float* __restrict__ out) {
    const int lane = threadIdx.x;   // 64 threads, one per image
    float s0 = 0.f, s1 = 0.f;
    #pragma unroll
    for (int j = 0; j < NSTRIP; ++j) {
        const float2 pp = partials[lane * NSTRIP + j];
        s0 += pp.x; s1 += pp.y;
    }
    float q = s1 / s0;
    q = wave_reduce(q);
    if (lane == 0) out[0] = q * (1.0f / (float)BATCH);
}

extern "C" void kernel_launch(void* const* d_in, const int* in_sizes, int n_in,
                              void* d_out, int out_size, void* d_ws, size_t ws_size,
                              hipStream_t stream) {
    const float* pred = (const float*)d_in[0];
    const float* mask = (const float*)d_in[1];
    float2* partials = (float2*)d_ws;   // 1024 * 8B

    hipLaunchKernelGGL(fused_kernel, dim3(BATCH * NSTRIP), dim3(512), 0, stream,
                       pred, mask, partials);
    hipLaunchKernelGGL(finalize_kernel, dim3(1), dim3(64), 0, stream,
                       partials, (float*)d_out);
}